// Round 3
// baseline (309.121 us; speedup 1.0000x reference)
//
#include <hip/hip_runtime.h>

#define NPTS  65536
#define NNEI  32
#define NKP   15
#define INF   64
#define OUTF  128
#define PPB   16            // points per block
#define KT_N  30            // 960 / 32 k-tiles
#define INV_KPE 41.666666666666664f
#define BN_EPS 1e-6f
#define NEG_SLOPE 0.1f

typedef __attribute__((ext_vector_type(8))) short  bf16x8;
typedef __attribute__((ext_vector_type(4))) float  f32x4;

// device-global scratch: no assumptions about ws_size
__device__ unsigned short g_Wp[KT_N * 8 * 64 * 8];   // 122880 bf16 elems = 240 KB
__device__ float g_ssum[OUTF];
__device__ float g_ssq[OUTF];
__device__ float g_scale[OUTF];
__device__ float g_shift[OUTF];

__device__ __forceinline__ unsigned short f2b(float f) {
    union { float f; unsigned int i; } v; v.f = f;
    unsigned int x = v.i;
    unsigned int r = (x + 0x7fffu + ((x >> 16) & 1u)) >> 16;   // RNE
    return (unsigned short)r;
}

// ---------------- Kernel 0: pack W[15][64][128] (f32) -> bf16 MFMA B-fragment layout.
// g_Wp[((kt*8 + nt)*64 + lane)*8 + j] = bf16(W[kd][o]) with W viewed [960][128],
//   kd = kt*32 + (lane>>4)*8 + j,  o = nt*16 + (lane&15)
// Block 0 also zeroes BN stat accumulators (runs before bn_stats in stream order).
__global__ __launch_bounds__(256) void pack_w(const float* __restrict__ W) {
    if (blockIdx.x == 0) {
        const int t = threadIdx.x;
        if (t < OUTF)            g_ssum[t] = 0.0f;
        else if (t < 2 * OUTF)   g_ssq[t - OUTF] = 0.0f;
    }
    int id = blockIdx.x * 256 + threadIdx.x;       // 122880 total
    int j  = id & 7;
    int ln = (id >> 3) & 63;
    int nt = (id >> 9) & 7;
    int kt = id >> 12;
    int kd = kt * 32 + ((ln >> 4) * 8) + j;
    int o  = nt * 16 + (ln & 15);
    g_Wp[id] = f2b(W[kd * OUTF + o]);
}

// ---------------- Kernel 1: fused KPConv
// Stage A (fp32 VALU): weighted[16 pts][960] -> LDS (bf16, MFMA-A fragment-major, XOR-swizzled)
// Stage B (MFMA bf16, fp32 acc): [16 x 960] @ [960 x 128] -> pre-BN x (f32) into d_out
__global__ __launch_bounds__(256) void kpconv_fused(
        const float* __restrict__ qp,    // [N][3]
        const float* __restrict__ sp,    // [N0][3]
        const int*   __restrict__ nbr,   // [N][32]
        const float* __restrict__ feat,  // [N0][64]
        const float* __restrict__ kp,    // [15][3]
        float*       __restrict__ out)   // [N][128] pre-BN x (f32)
{
    // weighted, fragment-major: elem (pl, kd) at ((kd>>3)*16 + (pl ^ ((kd>>3)&7)))*8 + (kd&7)
    __shared__ unsigned short wlds[120 * PPB * 8];   // 30720 B
    __shared__ float wbuf[4][NNEI][17];              // stride 17: conflict-free writes
    __shared__ int   ibuf[4][NNEI];
    __shared__ float kpts[NKP * 3];

    const int tid  = threadIdx.x;
    const int lane = tid & 63;
    const int wv   = tid >> 6;

    if (tid < NKP * 3) kpts[tid] = kp[tid];
    __syncthreads();

    // ---------------- Stage A: each wave computes weighted[15][64] for 4 points
    for (int it = 0; it < 4; ++it) {
        const int pl = wv * 4 + it;                    // local point 0..15
        const int gp = blockIdx.x * PPB + pl;          // global point

        if (lane < NNEI) {
            const int idx = nbr[gp * NNEI + lane];
            ibuf[wv][lane] = idx;
            const float dx = sp[idx * 3 + 0] - qp[gp * 3 + 0];
            const float dy = sp[idx * 3 + 1] - qp[gp * 3 + 1];
            const float dz = sp[idx * 3 + 2] - qp[gp * 3 + 2];
#pragma unroll
            for (int k = 0; k < NKP; ++k) {
                const float ex = dx - kpts[k * 3 + 0];
                const float ey = dy - kpts[k * 3 + 1];
                const float ez = dz - kpts[k * 3 + 2];
                const float s  = ex * ex + ey * ey + ez * ez;
                const float w  = 1.0f - sqrtf(s) * INV_KPE;
                wbuf[wv][lane][k] = (w > 0.0f) ? w : 0.0f;
            }
        }
        // same-wave LDS ops are in-order: reads below see the writes above

        float acc[NKP];
#pragma unroll
        for (int k = 0; k < NKP; ++k) acc[k] = 0.0f;

#pragma unroll 4
        for (int m = 0; m < NNEI; ++m) {
            const int idx = ibuf[wv][m];
            const float f = feat[idx * INF + lane];        // 256B coalesced per m
            const float* wr = &wbuf[wv][m][0];             // broadcast reads (free)
#pragma unroll
            for (int k = 0; k < NKP; ++k) acc[k] += wr[k] * f;
        }

        // store weighted (kd = k*64 + lane) in fragment-major + XOR swizzle
        const int h = lane >> 3;                  // = (kd>>3)&7 since k*8 ≡ 0 (mod 8)
        const int plx = pl ^ h;
#pragma unroll
        for (int k = 0; k < NKP; ++k) {
            const int g = k * 8 + h;              // kd>>3
            wlds[(g * PPB + plx) * 8 + (lane & 7)] = f2b(acc[k]);
        }
    }
    __syncthreads();

    // ---------------- Stage B: 16x960 @ 960x128, mfma 16x16x32 bf16
    // wave wv owns n-tiles {2wv, 2wv+1}; A-frag: row = lane&15, kd = kt*32 + (lane>>4)*8 + j
    const int q   = lane >> 4;
    const int m16 = lane & 15;
    const int nt0 = wv * 2;
    f32x4 acc0 = {0.f, 0.f, 0.f, 0.f};
    f32x4 acc1 = {0.f, 0.f, 0.f, 0.f};

    for (int kt = 0; kt < KT_N; ++kt) {
        const int g = kt * 4 + q;                 // kd>>3
        const bf16x8 a  = *(const bf16x8*)&wlds[(g * PPB + (m16 ^ (g & 7))) * 8];
        const bf16x8 b0 = *(const bf16x8*)&g_Wp[((kt * 8 + nt0) * 64 + lane) * 8];
        const bf16x8 b1 = *(const bf16x8*)&g_Wp[((kt * 8 + nt0 + 1) * 64 + lane) * 8];
        acc0 = __builtin_amdgcn_mfma_f32_16x16x32_bf16(a, b0, acc0, 0, 0, 0);
        acc1 = __builtin_amdgcn_mfma_f32_16x16x32_bf16(a, b1, acc1, 0, 0, 0);
    }

    // C/D layout: col = lane&15, row = (lane>>4)*4 + reg
    const int rbase = blockIdx.x * PPB + q * 4;
    const int c0 = nt0 * 16 + m16;
#pragma unroll
    for (int r = 0; r < 4; ++r) out[(rbase + r) * OUTF + c0]      = acc0[r];
#pragma unroll
    for (int r = 0; r < 4; ++r) out[(rbase + r) * OUTF + c0 + 16] = acc1[r];
}

// ---------------- Kernel 2: per-channel sum / sumsq of pre-BN x (f32)
__global__ __launch_bounds__(256) void bn_stats(const float* __restrict__ x) {
    __shared__ float sh[512];
    const int t  = threadIdx.x;
    const int o  = t & 127;
    const int r0 = blockIdx.x * 256 + ((t >> 7) * 128);
    float s = 0.f, q = 0.f;
    for (int r = r0; r < r0 + 128; ++r) {
        const float v = x[r * OUTF + o];
        s += v; q += v * v;
    }
    sh[t] = s; sh[256 + t] = q;
    __syncthreads();
    if (t < 128) {
        atomicAdd(&g_ssum[t], sh[t] + sh[t + 128]);
        atomicAdd(&g_ssq[t],  sh[256 + t] + sh[256 + t + 128]);
    }
}

// ---------------- Kernel 2b: per-channel scale/shift
__global__ void bn_scaleshift(const float* __restrict__ gamma,
                              const float* __restrict__ beta) {
    const int o = threadIdx.x;      // 128 threads
    const float inv_n = 1.0f / (float)NPTS;
    const float mean  = g_ssum[o] * inv_n;
    const float var   = g_ssq[o] * inv_n - mean * mean;
    const float sc    = gamma[o] * rsqrtf(var + BN_EPS);
    g_scale[o] = sc;
    g_shift[o] = beta[o] - mean * sc;
}

// ---------------- Kernel 3: in-place normalize + LeakyReLU (float4 / thread)
__global__ __launch_bounds__(256) void bn_norm(float* __restrict__ x) {
    const int id   = blockIdx.x * 256 + threadIdx.x;
    const int base = id * 4;
    const int o0   = base & 127;
    float4 v = *(const float4*)&x[base];
    const float4 sc = *(const float4*)&g_scale[o0];
    const float4 sf = *(const float4*)&g_shift[o0];
    float y0 = v.x * sc.x + sf.x;
    float y1 = v.y * sc.y + sf.y;
    float y2 = v.z * sc.z + sf.z;
    float y3 = v.w * sc.w + sf.w;
    y0 = (y0 >= 0.f) ? y0 : NEG_SLOPE * y0;
    y1 = (y1 >= 0.f) ? y1 : NEG_SLOPE * y1;
    y2 = (y2 >= 0.f) ? y2 : NEG_SLOPE * y2;
    y3 = (y3 >= 0.f) ? y3 : NEG_SLOPE * y3;
    float4 res = {y0, y1, y2, y3};
    *(float4*)&x[base] = res;
}

extern "C" void kernel_launch(void* const* d_in, const int* in_sizes, int n_in,
                              void* d_out, int out_size, void* d_ws, size_t ws_size,
                              hipStream_t stream) {
    const float* qp    = (const float*)d_in[0];
    const float* sp    = (const float*)d_in[1];
    const int*   nbr   = (const int*)d_in[2];
    const float* feat  = (const float*)d_in[3];
    const float* kp    = (const float*)d_in[4];
    const float* W     = (const float*)d_in[5];
    const float* gamma = (const float*)d_in[6];
    const float* beta  = (const float*)d_in[7];
    float* out = (float*)d_out;

    pack_w<<<480, 256, 0, stream>>>(W);
    kpconv_fused<<<NPTS / PPB, 256, 0, stream>>>(qp, sp, nbr, feat, kp, out);
    bn_stats<<<NPTS / 256, 256, 0, stream>>>(out);
    bn_scaleshift<<<1, 128, 0, stream>>>(gamma, beta);
    bn_norm<<<(NPTS * OUTF) / (256 * 4), 256, 0, stream>>>(out);
}

// Round 5
// 243.965 us; speedup vs baseline: 1.2671x; 1.2671x over previous
//
#include <hip/hip_runtime.h>

#define NPTS  65536
#define NNEI  32
#define NKP   15
#define INF   64
#define OUTF  128
#define PPB   32            // points per block
#define KT_N  30            // 960 / 32 k-tiles
#define INV_KPE 41.666666666666664f
#define BN_EPS 1e-6f
#define NEG_SLOPE 0.1f

typedef __attribute__((ext_vector_type(8))) short  bf16x8;
typedef __attribute__((ext_vector_type(4))) float  f32x4;

// device-global scratch (no assumptions about ws_size)
__device__ unsigned short g_Wp[KT_N * 8 * 64 * 8];     // 240 KB, MFMA B-frag layout
__device__ unsigned short g_featb[NPTS * INF];         // 8 MB, features as bf16
__device__ float g_ssum[OUTF], g_ssq[OUTF], g_scale[OUTF], g_shift[OUTF];

__device__ __forceinline__ unsigned short f2b(float f) {
    union { float f; unsigned int i; } v; v.f = f;
    unsigned int x = v.i;
    return (unsigned short)((x + 0x7fffu + ((x >> 16) & 1u)) >> 16);   // RNE
}
// pack two f32 -> two bf16 in one dword (HW cvt_pk if available, RNE either way)
__device__ __forceinline__ unsigned int pk2(float a, float b) {
#if __has_builtin(__builtin_amdgcn_cvt_pk_bf16_f32)
    auto r = __builtin_amdgcn_cvt_pk_bf16_f32(a, b);
    static_assert(sizeof(r) == 4, "cvt_pk_bf16 ret");
    unsigned int u; __builtin_memcpy(&u, &r, 4); return u;
#else
    return (unsigned int)f2b(a) | ((unsigned int)f2b(b) << 16);
#endif
}
__device__ __forceinline__ bf16x8 mk8(unsigned int a, unsigned int b,
                                      unsigned int c, unsigned int d) {
    unsigned int t[4] = {a, b, c, d};
    bf16x8 r; __builtin_memcpy(&r, t, 16); return r;
}

// swizzle for wlds (weighted) layout; conflict-free for both A-writes and B-reads
__device__ __forceinline__ int swz(int g) { return (((g >> 5) & 3) << 1) | (g & 1); }

// ---------------- Kernel 0: pack W -> bf16 B-frag layout, feat -> bf16, zero BN stats
__global__ __launch_bounds__(256) void pack_inputs(const float* __restrict__ W,
                                                   const float* __restrict__ feat) {
    const int b = blockIdx.x, t = threadIdx.x;
    if (b == 0) {
        if (t < OUTF)          g_ssum[t] = 0.0f;
        else if (t < 2 * OUTF) g_ssq[t - OUTF] = 0.0f;
    }
    if (b < 480) {                      // W: [960][128] f32 -> g_Wp
        int id = b * 256 + t;           // 122880 total
        int j  = id & 7;
        int ln = (id >> 3) & 63;
        int nt = (id >> 9) & 7;
        int kt = id >> 12;
        int kd = kt * 32 + ((ln >> 4) * 8) + j;
        int o  = nt * 16 + (ln & 15);
        g_Wp[id] = f2b(W[kd * OUTF + o]);
    } else {                            // feat: 4.19M f32 -> bf16, 4 per thread
        int id = (b - 480) * 256 + t;   // 1048576 float4s
        const float4 v = ((const float4*)feat)[id];
        uint2 r; r.x = pk2(v.x, v.y); r.y = pk2(v.z, v.w);
        ((uint2*)g_featb)[id] = r;
    }
}

// ---------------- Kernel 1: fused KPConv, both stages on MFMA
__global__ __launch_bounds__(256, 2) void kpconv_fused(
        const float* __restrict__ qp,    // [N][3]
        const float* __restrict__ sp,    // [N0][3]
        const int*   __restrict__ nbr,   // [N][32]
        const float* __restrict__ kp,    // [15][3]
        float*       __restrict__ out)   // [N][128] pre-BN x (f32)
{
    // weighted[pl][kd] at ((kd>>3)*PPB + (pl ^ swz(kd>>3)))*8 + (kd&7), bf16
    __shared__ unsigned short wlds[KT_N * 4 * PPB * 8];  // 61440 B
    __shared__ float dbuf[4][NNEI][3];                   // 1536 B: neighbor diffs
    __shared__ int   ibuf[4][NNEI];                      // 512 B
    __shared__ float kpts[48];                           // 192 B (pad kp -> huge dist)

    const int tid  = threadIdx.x;
    const int lane = tid & 63;
    const int wv   = tid >> 6;
    const int q    = lane >> 4;
    const int c16  = lane & 15;

    if (tid < 45)                 kpts[tid] = kp[tid];
    else if (tid < 48)            kpts[tid] = 1.0e6f;   // pad kernel point -> w = 0
    __syncthreads();

    const float kx = kpts[c16 * 3 + 0];
    const float ky = kpts[c16 * 3 + 1];
    const float kz = kpts[c16 * 3 + 2];

    // ---------------- Stage A: wave computes weighted[15][64] per point, 8 points
    for (int it = 0; it < 8; ++it) {
        const int pl = wv * 8 + it;
        const int gp = blockIdx.x * PPB + pl;

        if (lane < NNEI) {
            const int idx = nbr[gp * NNEI + lane];
            ibuf[wv][lane] = idx;
            dbuf[wv][lane][0] = sp[idx * 3 + 0] - qp[gp * 3 + 0];
            dbuf[wv][lane][1] = sp[idx * 3 + 1] - qp[gp * 3 + 1];
            dbuf[wv][lane][2] = sp[idx * 3 + 2] - qp[gp * 3 + 2];
        }
        // same-wave LDS ops are in-order: reads below see the writes above

        // B fragments: lane gathers feat_b[idx[q*8+j]][nt*16 + c16], j=0..7
        unsigned short uu[4][8];
#pragma unroll
        for (int j = 0; j < 8; ++j) {
            const int idx = ibuf[wv][q * 8 + j];
            const unsigned short* rowp = &g_featb[idx * INF + c16];
            uu[0][j] = rowp[0];  uu[1][j] = rowp[16];
            uu[2][j] = rowp[32]; uu[3][j] = rowp[48];
        }

        // A fragment: w[m = q*8+j][kp = c16] straight from diffs
        float w8[8];
#pragma unroll
        for (int j = 0; j < 8; ++j) {
            const int m = q * 8 + j;
            const float ex = dbuf[wv][m][0] - kx;
            const float ey = dbuf[wv][m][1] - ky;
            const float ez = dbuf[wv][m][2] - kz;
            const float s  = ex * ex + ey * ey + ez * ez;
            const float w  = 1.0f - __builtin_amdgcn_sqrtf(s) * INV_KPE;
            w8[j] = (w > 0.0f) ? w : 0.0f;
        }
        const bf16x8 af = mk8(pk2(w8[0], w8[1]), pk2(w8[2], w8[3]),
                              pk2(w8[4], w8[5]), pk2(w8[6], w8[7]));

        f32x4 acc[4] = {{0.f,0.f,0.f,0.f},{0.f,0.f,0.f,0.f},
                        {0.f,0.f,0.f,0.f},{0.f,0.f,0.f,0.f}};
#pragma unroll
        for (int nt = 0; nt < 4; ++nt) {
            const bf16x8 bfr = mk8(
                (unsigned int)uu[nt][0] | ((unsigned int)uu[nt][1] << 16),
                (unsigned int)uu[nt][2] | ((unsigned int)uu[nt][3] << 16),
                (unsigned int)uu[nt][4] | ((unsigned int)uu[nt][5] << 16),
                (unsigned int)uu[nt][6] | ((unsigned int)uu[nt][7] << 16));
            acc[nt] = __builtin_amdgcn_mfma_f32_16x16x32_bf16(af, bfr, acc[nt], 0, 0, 0);
        }

        // C: lane holds weighted[kp = q*4+r][chan = nt*16+c16]; store bf16 to wlds
#pragma unroll
        for (int nt = 0; nt < 4; ++nt) {
            const unsigned int p01 = pk2(acc[nt][0], acc[nt][1]);
            const unsigned int p23 = pk2(acc[nt][2], acc[nt][3]);
            const unsigned short cv[4] = {
                (unsigned short)p01, (unsigned short)(p01 >> 16),
                (unsigned short)p23, (unsigned short)(p23 >> 16)};
#pragma unroll
            for (int r = 0; r < 4; ++r) {
                const int kpp = q * 4 + r;
                if (kpp < NKP) {
                    const int kd = kpp * 64 + nt * 16 + c16;
                    const int g  = kd >> 3;
                    wlds[(g * PPB + (pl ^ swz(g))) * 8 + (kd & 7)] = cv[r];
                }
            }
        }
    }
    __syncthreads();

    // ---------------- Stage B: [32 x 960] @ [960 x 128]; wave: 2 m-tiles x 2 n-tiles
    const int nt0 = wv * 2;
    f32x4 a00 = {0.f,0.f,0.f,0.f}, a01 = {0.f,0.f,0.f,0.f};
    f32x4 a10 = {0.f,0.f,0.f,0.f}, a11 = {0.f,0.f,0.f,0.f};

    for (int kt = 0; kt < KT_N; ++kt) {
        const int g  = kt * 4 + q;
        const int cx = c16 ^ swz(g);
        const bf16x8 fa0 = *(const bf16x8*)&wlds[(g * PPB + cx) * 8];
        const bf16x8 fa1 = *(const bf16x8*)&wlds[(g * PPB + 16 + cx) * 8];
        const bf16x8 fb0 = *(const bf16x8*)&g_Wp[((kt * 8 + nt0) * 64 + lane) * 8];
        const bf16x8 fb1 = *(const bf16x8*)&g_Wp[((kt * 8 + nt0 + 1) * 64 + lane) * 8];
        a00 = __builtin_amdgcn_mfma_f32_16x16x32_bf16(fa0, fb0, a00, 0, 0, 0);
        a01 = __builtin_amdgcn_mfma_f32_16x16x32_bf16(fa0, fb1, a01, 0, 0, 0);
        a10 = __builtin_amdgcn_mfma_f32_16x16x32_bf16(fa1, fb0, a10, 0, 0, 0);
        a11 = __builtin_amdgcn_mfma_f32_16x16x32_bf16(fa1, fb1, a11, 0, 0, 0);
    }

    // C/D: col = lane&15, row = q*4 + r
    const int rb = blockIdx.x * PPB + q * 4;
    const int c0 = nt0 * 16 + c16;
#pragma unroll
    for (int r = 0; r < 4; ++r) {
        out[(rb + r) * OUTF + c0]           = a00[r];
        out[(rb + r) * OUTF + c0 + 16]      = a01[r];
        out[(rb + 16 + r) * OUTF + c0]      = a10[r];
        out[(rb + 16 + r) * OUTF + c0 + 16] = a11[r];
    }
}

// ---------------- Kernel 2: per-channel sum / sumsq of pre-BN x (f32)
__global__ __launch_bounds__(256) void bn_stats(const float* __restrict__ x) {
    __shared__ float sh[512];
    const int t  = threadIdx.x;
    const int o  = t & 127;
    const int r0 = blockIdx.x * 256 + ((t >> 7) * 128);
    float s = 0.f, qq = 0.f;
    for (int r = r0; r < r0 + 128; ++r) {
        const float v = x[r * OUTF + o];
        s += v; qq += v * v;
    }
    sh[t] = s; sh[256 + t] = qq;
    __syncthreads();
    if (t < 128) {
        atomicAdd(&g_ssum[t], sh[t] + sh[t + 128]);
        atomicAdd(&g_ssq[t],  sh[256 + t] + sh[256 + t + 128]);
    }
}

// ---------------- Kernel 2b: per-channel scale/shift
__global__ void bn_scaleshift(const float* __restrict__ gamma,
                              const float* __restrict__ beta) {
    const int o = threadIdx.x;      // 128 threads
    const float inv_n = 1.0f / (float)NPTS;
    const float mean  = g_ssum[o] * inv_n;
    const float var   = g_ssq[o] * inv_n - mean * mean;
    const float sc    = gamma[o] * rsqrtf(var + BN_EPS);
    g_scale[o] = sc;
    g_shift[o] = beta[o] - mean * sc;
}

// ---------------- Kernel 3: in-place normalize + LeakyReLU (float4 / thread)
__global__ __launch_bounds__(256) void bn_norm(float* __restrict__ x) {
    const int id   = blockIdx.x * 256 + threadIdx.x;
    const int base = id * 4;
    const int o0   = base & 127;
    float4 v = *(const float4*)&x[base];
    const float4 sc = *(const float4*)&g_scale[o0];
    const float4 sf = *(const float4*)&g_shift[o0];
    float y0 = v.x * sc.x + sf.x;
    float y1 = v.y * sc.y + sf.y;
    float y2 = v.z * sc.z + sf.z;
    float y3 = v.w * sc.w + sf.w;
    y0 = (y0 >= 0.f) ? y0 : NEG_SLOPE * y0;
    y1 = (y1 >= 0.f) ? y1 : NEG_SLOPE * y1;
    y2 = (y2 >= 0.f) ? y2 : NEG_SLOPE * y2;
    y3 = (y3 >= 0.f) ? y3 : NEG_SLOPE * y3;
    float4 res = {y0, y1, y2, y3};
    *(float4*)&x[base] = res;
}

extern "C" void kernel_launch(void* const* d_in, const int* in_sizes, int n_in,
                              void* d_out, int out_size, void* d_ws, size_t ws_size,
                              hipStream_t stream) {
    const float* qp    = (const float*)d_in[0];
    const float* sp    = (const float*)d_in[1];
    const int*   nbr   = (const int*)d_in[2];
    const float* feat  = (const float*)d_in[3];
    const float* kp    = (const float*)d_in[4];
    const float* W     = (const float*)d_in[5];
    const float* gamma = (const float*)d_in[6];
    const float* beta  = (const float*)d_in[7];
    float* out = (float*)d_out;

    pack_inputs<<<480 + 4096, 256, 0, stream>>>(W, feat);
    kpconv_fused<<<NPTS / PPB, 256, 0, stream>>>(qp, sp, nbr, kp, out);
    bn_stats<<<NPTS / 256, 256, 0, stream>>>(out);
    bn_scaleshift<<<1, 128, 0, stream>>>(gamma, beta);
    bn_norm<<<(NPTS * OUTF) / (256 * 4), 256, 0, stream>>>(out);
}